// Round 15
// baseline (247.383 us; speedup 1.0000x reference)
//
#include <hip/hip_runtime.h>
#include <math.h>
#include <stdint.h>

// ---------------------------------------------------------------------------
// SpatialDecoder: 3x { h = x @ W^T ; GAT edge softmax over dst ; mean ; ELU }
// NT = 32768 nodes, C = H = 256, E = 262144 edges.
// This round: (1) aggregate gather unrolled x8 (8 outstanding row loads; mean
// deg=8 -> single iteration for most nodes); (2) preprocessing consolidated:
// memsetAsync for cnt, single-block register-scan replaces 3 scan kernels.
// ---------------------------------------------------------------------------

typedef float f32x4 __attribute__((ext_vector_type(4)));
typedef _Float16 f16x8 __attribute__((ext_vector_type(8)));
typedef _Float16 f16x4 __attribute__((ext_vector_type(4)));

// ------------------------- merged f32 -> f16 conversion --------------------

__global__ __launch_bounds__(256) void convert_all(const float* __restrict__ x0,
                                                   _Float16* __restrict__ Xh, int nx,
                                                   const float* __restrict__ W0,
                                                   const float* __restrict__ W1,
                                                   const float* __restrict__ W2,
                                                   _Float16* __restrict__ Wh)
{
    const int i = (blockIdx.x * 256 + threadIdx.x) * 8;
    const float* src;
    _Float16* dstp;
    int off;
    if (i < nx) { src = x0; dstp = Xh; off = i; }
    else {
        const int j = i - nx;
        src = (j < 65536) ? W0 : ((j < 131072) ? W1 : W2);
        off = j & 65535;
        dstp = Wh + (j - off);      // Wh + layer*65536
    }
    float4 a = *(const float4*)&src[off];
    float4 b = *(const float4*)&src[off + 4];
    f16x8 o = {(_Float16)a.x, (_Float16)a.y, (_Float16)a.z, (_Float16)a.w,
               (_Float16)b.x, (_Float16)b.y, (_Float16)b.z, (_Float16)b.w};
    *(f16x8*)&dstp[off] = o;
}

// ------------------------- fp16 MFMA GEMM + row dots -----------------------
// Hout(M,256) = X(M,256) @ Wh(256,256)^T ; si = Hout@a[:256], sj = Hout@a[256:]
// 256 blocks x 512 threads. Block owns 128 rows; wave (wr,wc) owns 64x64 tile.
// Double-buffered LDS (2 x 48KB), 2-phase pipeline, 1 barrier per K-tile.

#define SWZ(row, byte) ((byte) ^ (((row) & 7) << 4))

__global__ __launch_bounds__(512) void gemm_f16(const _Float16* __restrict__ X,
                                                const _Float16* __restrict__ Wh,
                                                const float* __restrict__ avec,
                                                _Float16* __restrict__ Hout,
                                                float* __restrict__ si,
                                                float* __restrict__ sj)
{
    __shared__ __align__(16) unsigned char smem[98304];
    float (*Es)[260] = (float (*)[260])smem;

    const int tid  = threadIdx.x;
    const int lane = tid & 63;
    const int w    = tid >> 6;        // wave 0..7
    const int wr   = w >> 2;          // row half (64 rows)
    const int wc   = w & 3;           // col quarter (64 cols)
    const int ln   = lane & 15;
    const int kq   = lane >> 4;       // 0..3
    const int m0   = blockIdx.x * 128;

    const int xr = tid >> 2;          // X row 0..127
    const int xc = tid & 3;           // 32B chunk within 128B row-slice
    const int wrow = tid >> 1;        // W row 0..255
    const int wcb  = (tid & 1) * 64;  // byte offset within 128B row-slice

    const _Float16* Xg = X  + (size_t)(m0 + xr) * 256 + xc * 16;
    const _Float16* Wg = Wh + (size_t)wrow * 256 + wcb / 2;
    const int xs0 = SWZ(xr, xr * 128 + xc * 32);
    const int xs1 = SWZ(xr, xr * 128 + xc * 32 + 16);
    const int wl0 = 16384 + SWZ(wrow, wrow * 128 + wcb + 0);
    const int wl1 = 16384 + SWZ(wrow, wrow * 128 + wcb + 16);
    const int wl2 = 16384 + SWZ(wrow, wrow * 128 + wcb + 32);
    const int wl3 = 16384 + SWZ(wrow, wrow * 128 + wcb + 48);

    f32x4 acc[4][4] = {};

    // ---- prologue: stage K-tile 0 into buffer 0 ----
    f16x8 x0 = *(const f16x8*)&Xg[0];
    f16x8 x1 = *(const f16x8*)&Xg[8];
    f16x8 w0 = *(const f16x8*)&Wg[0];
    f16x8 w1 = *(const f16x8*)&Wg[8];
    f16x8 w2 = *(const f16x8*)&Wg[16];
    f16x8 w3 = *(const f16x8*)&Wg[24];
    *(f16x8*)(smem + xs0) = x0;  *(f16x8*)(smem + xs1) = x1;
    *(f16x8*)(smem + wl0) = w0;  *(f16x8*)(smem + wl1) = w1;
    *(f16x8*)(smem + wl2) = w2;  *(f16x8*)(smem + wl3) = w3;
    __syncthreads();

#pragma unroll
    for (int t = 0; t < 4; ++t) {
        const int cb = (t & 1) * 49152;          // current buffer
        const int nb = ((t & 1) ^ 1) * 49152;    // next buffer
        if (t < 3) {
            const int k0 = (t + 1) * 64;
            x0 = *(const f16x8*)&Xg[k0];
            x1 = *(const f16x8*)&Xg[k0 + 8];
            w0 = *(const f16x8*)&Wg[k0];
            w1 = *(const f16x8*)&Wg[k0 + 8];
            w2 = *(const f16x8*)&Wg[k0 + 16];
            w3 = *(const f16x8*)&Wg[k0 + 24];
        }
#pragma unroll
        for (int kk = 0; kk < 2; ++kk) {
            f16x8 af[4], bf[4];
#pragma unroll
            for (int i = 0; i < 4; ++i) {
                const int row = wr * 64 + i * 16 + ln;
                af[i] = *(const f16x8*)(smem + cb + SWZ(row, row * 128 + kk * 64 + kq * 16));
            }
#pragma unroll
            for (int j = 0; j < 4; ++j) {
                const int row = wc * 64 + j * 16 + ln;
                bf[j] = *(const f16x8*)(smem + cb + 16384 + SWZ(row, row * 128 + kk * 64 + kq * 16));
            }
#pragma unroll
            for (int i = 0; i < 4; ++i)
#pragma unroll
                for (int j = 0; j < 4; ++j)
                    acc[i][j] = __builtin_amdgcn_mfma_f32_16x16x32_f16(af[i], bf[j], acc[i][j], 0, 0, 0);
        }
        if (t < 3) {
            *(f16x8*)(smem + nb + xs0) = x0;  *(f16x8*)(smem + nb + xs1) = x1;
            *(f16x8*)(smem + nb + wl0) = w0;  *(f16x8*)(smem + nb + wl1) = w1;
            *(f16x8*)(smem + nb + wl2) = w2;  *(f16x8*)(smem + nb + wl3) = w3;
        }
        __syncthreads();
    }

    // ---- epilogue: per 16-row group, LDS transpose + f16 store + fused dots ----
    const int er = tid >> 5;          // 0..15
    const int ec = tid & 31;          // 0..31
    for (int g = 0; g < 8; ++g) {
        if (wr == (g >> 2)) {
            const int i = g & 3;
#pragma unroll
            for (int j = 0; j < 4; ++j) {
                const int col = wc * 64 + j * 16 + ln;
#pragma unroll
                for (int q = 0; q < 4; ++q)
                    Es[kq * 4 + q][col] = acc[i][j][q];
            }
        }
        __syncthreads();
        const int grow = m0 + g * 16 + er;
        const int c0 = ec * 8;
        f32x4 v0 = *(const f32x4*)&Es[er][c0];
        f32x4 v1 = *(const f32x4*)&Es[er][c0 + 4];
        f16x8 ho = {(_Float16)v0[0], (_Float16)v0[1], (_Float16)v0[2], (_Float16)v0[3],
                    (_Float16)v1[0], (_Float16)v1[1], (_Float16)v1[2], (_Float16)v1[3]};
        *(f16x8*)&Hout[(size_t)grow * 256 + c0] = ho;

        f32x4 al0 = *(const f32x4*)&avec[c0];
        f32x4 al1 = *(const f32x4*)&avec[c0 + 4];
        f32x4 ah0 = *(const f32x4*)&avec[256 + c0];
        f32x4 ah1 = *(const f32x4*)&avec[256 + c0 + 4];
        float d0 = v0[0]*al0[0] + v0[1]*al0[1] + v0[2]*al0[2] + v0[3]*al0[3]
                 + v1[0]*al1[0] + v1[1]*al1[1] + v1[2]*al1[2] + v1[3]*al1[3];
        float d1 = v0[0]*ah0[0] + v0[1]*ah0[1] + v0[2]*ah0[2] + v0[3]*ah0[3]
                 + v1[0]*ah1[0] + v1[1]*ah1[1] + v1[2]*ah1[2] + v1[3]*ah1[3];
#pragma unroll
        for (int d = 16; d; d >>= 1) {
            d0 += __shfl_xor(d0, d);
            d1 += __shfl_xor(d1, d);
        }
        if (ec == 0) { si[grow] = d0; sj[grow] = d1; }
        __syncthreads();
    }
}

// ------------------------- edge preprocessing ------------------------------

__global__ void hist_kernel(const int* __restrict__ dst, int* __restrict__ cnt, int E)
{
    int e = blockIdx.x * blockDim.x + threadIdx.x;
    if (e < E) atomicAdd(&cnt[dst[e]], 1);
}

// Single-block scan: 1024 threads x 32 elements each (NT = 32768).
__global__ __launch_bounds__(1024) void scan_fused(const int* __restrict__ cnt,
                                                   int* __restrict__ off,
                                                   int* __restrict__ cursor,
                                                   int NT, int E)
{
    __shared__ int ts[1024];
    const int tid = threadIdx.x;
    const int base = tid * 32;
    int v[32];
    int s = 0;
#pragma unroll
    for (int i = 0; i < 32; i += 4) {
        int4 q = *(const int4*)&cnt[base + i];
        v[i] = q.x; v[i+1] = q.y; v[i+2] = q.z; v[i+3] = q.w;
        s += q.x + q.y + q.z + q.w;
    }
    ts[tid] = s;
    __syncthreads();
#pragma unroll
    for (int d = 1; d < 1024; d <<= 1) {
        int t = (tid >= d) ? ts[tid - d] : 0;
        __syncthreads();
        ts[tid] += t;
        __syncthreads();
    }
    int run = ts[tid] - s;     // exclusive prefix of this thread's chunk
#pragma unroll
    for (int i = 0; i < 32; ++i) {
        off[base + i] = run;
        cursor[base + i] = run;
        run += v[i];
    }
    if (tid == 1023) off[NT] = E;
}

__global__ void scatter_kernel(const int* __restrict__ src,
                               const int* __restrict__ dst,
                               int* __restrict__ cursor,
                               int* __restrict__ ssrc, int E)
{
    int e = blockIdx.x * blockDim.x + threadIdx.x;
    if (e < E) {
        int p = atomicAdd(&cursor[dst[e]], 1);
        ssrc[p] = src[e];
    }
}

// ------------------------- per-node softmax + aggregate --------------------
// One wave per node. Fast path (deg<=64): lane=edge score+softmax in one pass,
// then x8-unrolled row gather (8 outstanding loads) w/ readlane broadcast.
// F16OUT=1: write f16 (next layer's GEMM input). F16OUT=0: write f32 (d_out).

__device__ __forceinline__ float bcast_f(float x, int l)
{
    return __uint_as_float(__builtin_amdgcn_readlane(__float_as_uint(x), l));
}

template <int F16OUT>
__global__ __launch_bounds__(256) void aggregate(const _Float16* __restrict__ Hh,
                                                 const float* __restrict__ si,
                                                 const float* __restrict__ sj,
                                                 const int* __restrict__ off,
                                                 const int* __restrict__ ssrc,
                                                 void* __restrict__ outv,
                                                 int n_nodes)
{
    const int v = (blockIdx.x * 256 + threadIdx.x) >> 6;   // one wave per node
    const int lane = threadIdx.x & 63;
    if (v >= n_nodes) return;

    const int e0 = off[v], e1 = off[v + 1];
    const int deg = e1 - e0;
    f32x4 acc = {0.f, 0.f, 0.f, 0.f};

    if (deg > 0 && deg <= 64) {
        const float siv = si[v];
        // edge-parallel score: lane l owns edge e0+l
        const int idx = e0 + lane;
        const bool on = idx < e1;
        int s = 0;
        float scv = -1e30f;
        if (on) {
            s = ssrc[idx];
            float t = siv + sj[s];
            scv = (t >= 0.f) ? t : 0.2f * t;
        }
        float m = scv;
#pragma unroll
        for (int d = 32; d; d >>= 1) m = fmaxf(m, __shfl_xor(m, d));
        float wv = on ? __expf(scv - m) : 0.f;
        float den = wv;
#pragma unroll
        for (int d = 32; d; d >>= 1) den += __shfl_xor(den, d);

        // column-parallel gather, unroll 8: 8 outstanding 512B row loads.
        // Lanes >= deg have wv=0 -> their (clamped) rows contribute exact 0.
        const int c4 = lane * 4;
        for (int eo = 0; eo < deg; eo += 8) {
            int sl[8]; float wl[8];
#pragma unroll
            for (int u = 0; u < 8; ++u) {
                const int l = (eo + u < 63) ? eo + u : 63;
                sl[u] = __builtin_amdgcn_readlane(s, l);
                wl[u] = bcast_f(wv, l);
            }
            f16x4 hv[8];
#pragma unroll
            for (int u = 0; u < 8; ++u)
                hv[u] = *(const f16x4*)&Hh[(size_t)sl[u] * 256 + c4];
#pragma unroll
            for (int q = 0; q < 4; ++q) {
                float t = 0.f;
#pragma unroll
                for (int u = 0; u < 8; ++u)
                    t += wl[u] * (float)hv[u][q];
                acc[q] += t;
            }
        }
        const float inv = 1.f / (den * (float)deg);
#pragma unroll
        for (int q = 0; q < 4; ++q) acc[q] *= inv;
    } else if (deg > 64) {
        // generic fallback (rare): 3-pass lane-strided
        const float siv = si[v];
        float m = -1e30f;
        for (int b = e0 + lane; b < e1; b += 64) {
            float t = siv + sj[ssrc[b]];
            t = (t >= 0.f) ? t : 0.2f * t;
            m = fmaxf(m, t);
        }
#pragma unroll
        for (int d = 32; d; d >>= 1) m = fmaxf(m, __shfl_xor(m, d));
        float den = 0.f;
        for (int b = e0 + lane; b < e1; b += 64) {
            float t = siv + sj[ssrc[b]];
            t = (t >= 0.f) ? t : 0.2f * t;
            den += __expf(t - m);
        }
#pragma unroll
        for (int d = 32; d; d >>= 1) den += __shfl_xor(den, d);
        for (int e = e0; e < e1; ++e) {
            const int s = ssrc[e];
            float t = siv + sj[s];
            t = (t >= 0.f) ? t : 0.2f * t;
            const float wgt = __expf(t - m);
            const f16x4 hv = *(const f16x4*)&Hh[(size_t)s * 256 + lane * 4];
#pragma unroll
            for (int q = 0; q < 4; ++q) acc[q] += wgt * (float)hv[q];
        }
        const float inv = 1.f / (den * (float)deg);
#pragma unroll
        for (int q = 0; q < 4; ++q) acc[q] *= inv;
    }

    // ELU + store
    float4 o;
    o.x = (acc[0] > 0.f) ? acc[0] : (__expf(acc[0]) - 1.f);
    o.y = (acc[1] > 0.f) ? acc[1] : (__expf(acc[1]) - 1.f);
    o.z = (acc[2] > 0.f) ? acc[2] : (__expf(acc[2]) - 1.f);
    o.w = (acc[3] > 0.f) ? acc[3] : (__expf(acc[3]) - 1.f);
    if (F16OUT) {
        f16x4 oh = {(_Float16)o.x, (_Float16)o.y, (_Float16)o.z, (_Float16)o.w};
        *(f16x4*)&((_Float16*)outv)[(size_t)v * 256 + lane * 4] = oh;
    } else {
        *(float4*)&((float*)outv)[(size_t)v * 256 + lane * 4] = o;
    }
}

// ---------------------------------------------------------------------------

extern "C" void kernel_launch(void* const* d_in, const int* in_sizes, int n_in,
                              void* d_out, int out_size, void* d_ws, size_t ws_size,
                              hipStream_t stream)
{
    const float* x0 = (const float*)d_in[0];
    const int*   ei = (const int*)d_in[1];      // (2,E) int32: row0=src, row1=dst
    const float* Ws[3] = {(const float*)d_in[2], (const float*)d_in[4], (const float*)d_in[6]};
    const float* as[3] = {(const float*)d_in[3], (const float*)d_in[5], (const float*)d_in[7]};
    float* out = (float*)d_out;

    const int NT = in_sizes[0] / 256;   // 32768
    const int E  = in_sizes[1] / 2;     // 262144
    const int* srcI = ei;
    const int* dstI = ei + E;

    // workspace layout (~34 MB)
    _Float16* Hh = (_Float16*)d_ws;                 // NT*256 f16
    _Float16* Xh = Hh + (size_t)NT * 256;           // NT*256 f16 (layer input)
    float* si    = (float*)(Xh + (size_t)NT * 256);
    float* sj    = si + NT;
    int* cnt     = (int*)(sj + NT);
    int* off     = cnt + NT;            // NT+1 entries
    int* cursor  = off + NT + 1;
    int* ssrc    = cursor + NT;         // E entries
    int* bsum    = ssrc + E;            // spare
    _Float16* Wh = (_Float16*)(((uintptr_t)(bsum + 64) + 255) & ~(uintptr_t)255);

    // all f32->f16 conversions in one launch (x0 then W0|W1|W2)
    const int nx = NT * 256;
    convert_all<<<(nx + 3 * 65536) / 2048, 256, 0, stream>>>(x0, Xh, nx,
                                                             Ws[0], Ws[1], Ws[2], Wh);

    // edge preprocessing (layer-invariant)
    hipMemsetAsync(cnt, 0, (size_t)NT * sizeof(int), stream);
    hist_kernel<<<(E + 255) / 256, 256, 0, stream>>>(dstI, cnt, E);
    scan_fused<<<1, 1024, 0, stream>>>(cnt, off, cursor, NT, E);
    scatter_kernel<<<(E + 255) / 256, 256, 0, stream>>>(srcI, dstI, cursor, ssrc, E);

    for (int l = 0; l < 3; ++l) {
        gemm_f16<<<NT / 128, 512, 0, stream>>>(Xh, Wh + (size_t)l * 65536, as[l], Hh, si, sj);
        if (l < 2)
            aggregate<1><<<NT / 4, 256, 0, stream>>>(Hh, si, sj, off, ssrc, (void*)Xh, NT);
        else
            aggregate<0><<<NT / 4, 256, 0, stream>>>(Hh, si, sj, off, ssrc, (void*)out, NT);
    }
}